// Round 1
// baseline (49641.101 us; speedup 1.0000x reference)
//
#include <hip/hip_runtime.h>
#include <stdint.h>
#include <stddef.h>

#define T_ 512
#define B_ 128
#define D_ 400
#define H_ 400
#define HP 416
#define GP 1664            // 4*HP (per-dir padded gate dim)
#define NW 3328            // both dirs stacked
#define K0P 448            // padded K for layer 0 GEMM
#define K12P 832           // padded K for layers 1,2 GEMM
#define NTILES 13          // h tiles of 32 per dir
#define NGRP 8             // batch groups of 16
#define REC_BLOCKS 208     // 2*8*13

// ---- recurrent-kernel LDS layout (bytes) ----
#define WHH_BYTES (128*424*2)            // 108544
#define HS_OFF    WHH_BYTES
#define HS_BYTES  (16*424*2)             // 13568
#define GC_OFF    (HS_OFF + HS_BYTES)    // 122112
#define GC_FSTRIDE 576                   // floats per gate region (16*36)
#define GC_BYTES  (4*GC_FSTRIDE*4)       // 9216
#define GXS_OFF   (GC_OFF + GC_BYTES)    // 131328
#define GXS_BYTES (16*132*4)             // 8448
#define LDS_TOTAL (GXS_OFF + GXS_BYTES)  // 139776

typedef __attribute__((ext_vector_type(8))) __bf16 bf16x8;
typedef __attribute__((ext_vector_type(4))) float f32x4;
typedef __attribute__((ext_vector_type(8))) unsigned short us8;

__device__ __forceinline__ unsigned short f2bf(float f){
  unsigned u = __builtin_bit_cast(unsigned, f);
  u = (u + 0x7FFFu + ((u >> 16) & 1u)) >> 16;
  return (unsigned short)u;
}
__device__ __forceinline__ float bf2f(unsigned short s){
  unsigned u = ((unsigned)s) << 16;
  return __builtin_bit_cast(float, u);
}
__device__ __forceinline__ float sigm(float x){ return 1.f / (1.f + __expf(-x)); }
__device__ __forceinline__ float tanh_f(float x){
  float ax = fabsf(x);
  float e = __expf(-2.f * ax);
  float t = (1.f - e) / (1.f + e);
  return x < 0.f ? -t : t;
}
__device__ __forceinline__ void store_gx(float* p, float v){ *p = v; }
__device__ __forceinline__ void store_gx(unsigned short* p, float v){ *p = f2bf(v); }

// ======================= prep kernels =======================
__global__ void k_conv_x0(const float* __restrict__ x, unsigned short* __restrict__ xa){
  const size_t i = (size_t)blockIdx.x*256 + threadIdx.x;
  if (i >= (size_t)T_*B_*K0P) return;
  const int k = (int)(i % K0P);
  const size_t tb = i / K0P;
  xa[i] = f2bf(k < D_ ? x[tb*D_ + k] : 0.f);
}

__global__ void k_prep_wih(const float* __restrict__ wf, const float* __restrict__ wb,
                           int K, int mode, unsigned short* __restrict__ dst){
  const size_t i = (size_t)blockIdx.x*256 + threadIdx.x;
  if (i >= (size_t)NW*K) return;
  const int k = (int)(i % K);
  const int n = (int)(i / K);
  const int d = n / GP, ng = n % GP, g = ng / HP, r = ng % HP;
  const float* Wsrc = d ? wb : wf;
  float v = 0.f;
  if (r < H_){
    if (mode == 0){                       // layer 0: K real 400
      if (k < D_) v = Wsrc[(size_t)(g*H_ + r)*D_ + k];
    } else {                              // layers 1,2: [fwd400|pad16|bwd400|pad16]
      int ks = (k < 400) ? k : ((k >= 416 && k < 816) ? (k - 16) : -1);
      if (ks >= 0) v = Wsrc[(size_t)(g*H_ + r)*800 + ks];
    }
  }
  dst[i] = f2bf(v);
}

__global__ void k_prep_whh(const float* __restrict__ wf, const float* __restrict__ wb,
                           unsigned short* __restrict__ dst){
  const size_t i = (size_t)blockIdx.x*256 + threadIdx.x;
  if (i >= (size_t)2*NTILES*128*424) return;
  const int k = (int)(i % 424);
  size_t r1 = i / 424;
  const int nloc = (int)(r1 % 128);
  size_t r2 = r1 / 128;
  const int tile = (int)(r2 % NTILES);
  const int d = (int)(r2 / NTILES);
  const int g = nloc >> 5, rr = nloc & 31;
  const int c = tile*32 + rr;
  const float* Wsrc = d ? wb : wf;
  float v = (c < H_ && k < H_) ? Wsrc[(size_t)(g*H_ + c)*H_ + k] : 0.f;
  dst[i] = f2bf(v);
}

__global__ void k_prep_bias(const float* __restrict__ bsf, const float* __restrict__ bsb,
                            float* __restrict__ dst){
  const int n = blockIdx.x*256 + threadIdx.x;
  if (n >= NW) return;
  const int d = n / GP, ng = n % GP, g = ng / HP, r = ng % HP;
  dst[n] = (r < H_) ? (d ? bsb : bsf)[g*H_ + r] : 0.f;
}

// ======================= gx GEMM =======================
// C[t*128+b][n] = X[t,b,:] . W[n,:] + bias[n]   (W supplied as [NW][K], i.e. B^T form)
template<typename GXT>
__global__ __launch_bounds__(256) void gemm_gx(
    const unsigned short* __restrict__ X, int lda, int K,
    const unsigned short* __restrict__ W,
    const float* __restrict__ bias,
    GXT* __restrict__ gx,
    const int* __restrict__ lens)
{
  const int t = blockIdx.y;
  if (t >= lens[0]) return;                 // gx at t >= max_len is never read
  const int n0 = blockIdx.x * 128;
  __shared__ unsigned short As[128*64];
  __shared__ unsigned short Bs[128*64];
  const int tid = threadIdx.x;
  const int l = tid & 63;
  const int w = tid >> 6;
  const int wm = (w >> 1) * 64, wn = (w & 1) * 64;
  const int lr = l & 15, lk = l >> 4;
  f32x4 acc[4][4];
  #pragma unroll
  for (int i = 0; i < 4; ++i)
    #pragma unroll
    for (int j = 0; j < 4; ++j) acc[i][j] = (f32x4){0.f,0.f,0.f,0.f};

  const unsigned short* Xb = X + (size_t)t * B_ * lda;
  const int r_ = tid >> 3, s_ = (tid & 7) * 8;

  for (int k0 = 0; k0 < K; k0 += 64){
    us8 va[4], vb[4];
    #pragma unroll
    for (int i = 0; i < 4; ++i){
      const int r = i*32 + r_;
      va[i] = *(const us8*)(Xb + (size_t)r*lda + k0 + s_);
      vb[i] = *(const us8*)(W  + (size_t)(n0 + r)*K + k0 + s_);
    }
    __syncthreads();
    #pragma unroll
    for (int i = 0; i < 4; ++i){
      const int r = i*32 + r_;
      *(us8*)&As[r*64 + s_] = va[i];
      *(us8*)&Bs[r*64 + s_] = vb[i];
    }
    __syncthreads();
    #pragma unroll
    for (int kk = 0; kk < 2; ++kk){
      bf16x8 af[4], bfr[4];
      #pragma unroll
      for (int mi = 0; mi < 4; ++mi)
        af[mi] = __builtin_bit_cast(bf16x8, *(const us8*)&As[(wm + mi*16 + lr)*64 + kk*32 + lk*8]);
      #pragma unroll
      for (int ni = 0; ni < 4; ++ni)
        bfr[ni] = __builtin_bit_cast(bf16x8, *(const us8*)&Bs[(wn + ni*16 + lr)*64 + kk*32 + lk*8]);
      #pragma unroll
      for (int mi = 0; mi < 4; ++mi)
        #pragma unroll
        for (int ni = 0; ni < 4; ++ni)
          acc[mi][ni] = __builtin_amdgcn_mfma_f32_16x16x32_bf16(af[mi], bfr[ni], acc[mi][ni], 0, 0, 0);
    }
  }
  #pragma unroll
  for (int ni = 0; ni < 4; ++ni){
    const int col = n0 + wn + ni*16 + lr;
    const float bv = bias[col];
    #pragma unroll
    for (int mi = 0; mi < 4; ++mi){
      #pragma unroll
      for (int r = 0; r < 4; ++r){
        const int b = wm + mi*16 + lk*4 + r;
        store_gx(gx + ((size_t)t*B_ + b)*NW + col, acc[mi][ni][r] + bv);
      }
    }
  }
}

// ======================= recurrent (cooperative) =======================
// grid: 208 blocks = dir(2) x group(8 of 16 batches) x htile(13 of 32 cols)
// wave w (of 4) owns gate w. Per-group 13-block monotonic barrier per step.
template<typename GXT, bool LAST>
__global__ __launch_bounds__(256) void lstm_rec(
    const GXT* __restrict__ gx,
    const unsigned short* __restrict__ whhp,   // [2][13][128][424] bf16
    const int* __restrict__ lens,
    unsigned short* hbuf,                      // [2*8][2][16][416] bf16
    unsigned short* xn,                        // [T][128][832] bf16 (or unused)
    float* out,                                // [T][128][800] f32 (or unused)
    unsigned int* ctr)                         // [16]
{
  extern __shared__ char smem[];
  unsigned short* WhhL = (unsigned short*)smem;
  unsigned short* HS   = (unsigned short*)(smem + HS_OFF);
  float* GC  = (float*)(smem + GC_OFF);
  float* GXS = (float*)(smem + GXS_OFF);

  const int tid = threadIdx.x;
  const int bid = blockIdx.x;
  const int dir  = bid / 104;
  const int rem  = bid % 104;
  const int grp  = rem / NTILES;
  const int tile = rem % NTILES;
  const int l  = tid & 63;
  const int w  = tid >> 6;
  const int lr = l & 15;
  const int lk = l >> 4;
  const int cid = dir*NGRP + grp;

  // Whh blob -> LDS (resident for whole kernel)
  {
    const unsigned short* src = whhp + (size_t)(dir*NTILES + tile) * (128*424);
    for (int i = tid; i < (128*424)/8; i += 256)
      *(us8*)&WhhL[i*8] = *(const us8*)(src + (size_t)i*8);
  }
  // zero this block's h slices (both parities)
  const size_t hgrp = (size_t)cid * 2 * 16 * HP;
  {
    int b = tid >> 4, c2 = (tid & 15) * 2;
    size_t o0 = hgrp + (size_t)b*HP + tile*32 + c2;
    *(unsigned int*)&hbuf[o0] = 0u;
    *(unsigned int*)&hbuf[o0 + (size_t)16*HP] = 0u;
  }
  const int grp_len = lens[grp*16];          // lens sorted desc -> group max
  const int eb  = tid & 15;                  // elementwise batch (fixed)
  const int ec0 = tid >> 4;                  // elementwise col (pair: +0,+16)
  const int mylen = lens[grp*16 + eb];
  float cs0 = 0.f, cs1 = 0.f, hs0 = 0.f, hs1 = 0.f;

  __threadfence();
  __syncthreads();
  if (tid == 0) __hip_atomic_fetch_add(&ctr[cid], 1u, __ATOMIC_RELEASE, __HIP_MEMORY_SCOPE_AGENT);

  int epoch = 1, par = 0;
  const int pb = tid >> 4, q = tid & 15, qg = q >> 2, qj = (q & 3) * 8;

  for (int s = 0; s < T_; ++s){
    const int t = dir ? (T_ - 1 - s) : s;
    if (t >= grp_len) continue;            // whole group idle: uniform, no barrier

    // prefetch gx for this step (independent of barrier)
    f32x4 pfa, pfb;
    {
      const size_t goff = ((size_t)t*B_ + grp*16 + pb) * NW + (size_t)dir*GP + qg*HP + tile*32 + qj;
      if constexpr (sizeof(GXT) == 4){
        const float* gp = (const float*)gx + goff;
        pfa = *(const f32x4*)gp;
        pfb = *(const f32x4*)(gp + 4);
      } else {
        us8 v = *(const us8*)((const unsigned short*)gx + goff);
        pfa = (f32x4){bf2f(v[0]), bf2f(v[1]), bf2f(v[2]), bf2f(v[3])};
        pfb = (f32x4){bf2f(v[4]), bf2f(v[5]), bf2f(v[6]), bf2f(v[7])};
      }
    }
    // wait for all 13 blocks of this group to publish h of previous step
    if (tid == 0){
      const unsigned tgt = 13u * (unsigned)epoch;
      while (__hip_atomic_load(&ctr[cid], __ATOMIC_ACQUIRE, __HIP_MEMORY_SCOPE_AGENT) < tgt)
        __builtin_amdgcn_s_sleep(1);
    }
    __syncthreads();
    __threadfence();                        // acquire: invalidate caches for fresh h

    // stage h (16 x 416) -> LDS, padded stride 424
    {
      const unsigned short* hsrc = hbuf + hgrp + (size_t)par*16*HP;
      for (int i = tid; i < 832; i += 256){
        int b = i / 52, sg = i % 52;
        *(us8*)&HS[b*424 + sg*8] = *(const us8*)(hsrc + b*HP + sg*8);
      }
    }
    __syncthreads();

    // gates[16 x 32] for gate w:  h(16x416) @ Whh_tile^T
    f32x4 a0 = (f32x4){0.f,0.f,0.f,0.f}, a1 = (f32x4){0.f,0.f,0.f,0.f};
    {
      const int ab  = lr*424 + lk*8;
      const int nb0 = (w*32 + lr)*424 + lk*8;
      const int nb1 = nb0 + 16*424;
      #pragma unroll
      for (int kk = 0; kk < 13; ++kk){
        bf16x8 av = __builtin_bit_cast(bf16x8, *(const us8*)&HS[ab + kk*32]);
        bf16x8 b0 = __builtin_bit_cast(bf16x8, *(const us8*)&WhhL[nb0 + kk*32]);
        bf16x8 b1 = __builtin_bit_cast(bf16x8, *(const us8*)&WhhL[nb1 + kk*32]);
        a0 = __builtin_amdgcn_mfma_f32_16x16x32_bf16(av, b0, a0, 0, 0, 0);
        a1 = __builtin_amdgcn_mfma_f32_16x16x32_bf16(av, b1, a1, 0, 0, 0);
      }
    }
    // publish gate partials + gx to LDS
    {
      float* Gw = GC + w * GC_FSTRIDE;
      #pragma unroll
      for (int r = 0; r < 4; ++r){
        Gw[(lk*4 + r)*36 + lr]      = a0[r];
        Gw[(lk*4 + r)*36 + 16 + lr] = a1[r];
      }
      float* gp = GXS + pb*132 + qg*32 + qj;
      *(f32x4*)gp = pfa;
      *(f32x4*)(gp + 4) = pfb;
    }
    __syncthreads();

    // elementwise LSTM cell: thread owns (b=eb, c in {ec0, ec0+16})
    const bool act = t < mylen;
    #pragma unroll
    for (int pp = 0; pp < 2; ++pp){
      const int c = ec0 + pp*16;
      const float gi = GC[0*GC_FSTRIDE + eb*36 + c] + GXS[eb*132 + c];
      const float gf = GC[1*GC_FSTRIDE + eb*36 + c] + GXS[eb*132 + 32 + c];
      const float gg = GC[2*GC_FSTRIDE + eb*36 + c] + GXS[eb*132 + 64 + c];
      const float go = GC[3*GC_FSTRIDE + eb*36 + c] + GXS[eb*132 + 96 + c];
      const float si = sigm(gi), sf = sigm(gf), so = sigm(go);
      const float tg = tanh_f(gg);
      float& cc = pp ? cs1 : cs0;
      float& hh = pp ? hs1 : hs0;
      const float cn = sf*cc + si*tg;
      const float hn = so * tanh_f(cn);
      if (act){ cc = cn; hh = hn; }
      // always publish (frozen value if masked) into the next parity buffer
      hbuf[hgrp + (size_t)(par^1)*16*HP + (size_t)eb*HP + tile*32 + c] = f2bf(hh);
      if (act){
        const int bg = grp*16 + eb;
        const int hc = tile*32 + c;
        if constexpr (LAST){
          if (hc < H_) out[((size_t)t*B_ + bg)*800 + dir*H_ + hc] = hh;
        } else {
          xn[((size_t)t*B_ + bg)*832 + (size_t)dir*HP + hc] = f2bf(hh);
        }
      }
    }
    __threadfence();        // release h writes (per thread)
    __syncthreads();
    if (tid == 0) __hip_atomic_fetch_add(&ctr[cid], 1u, __ATOMIC_RELEASE, __HIP_MEMORY_SCOPE_AGENT);
    ++epoch; par ^= 1;
  }
}

// ======================= host side =======================
template<typename GXT>
static void run_all(void* const* din, float* out, char* ws, hipStream_t stream)
{
  const float* x      = (const float*)din[0];
  const int* lens     = (const int*)din[1];
  const float* wihf0  = (const float*)din[2];
  const float* wihf12 = (const float*)din[3];
  const float* whhf   = (const float*)din[4];
  const float* bsf    = (const float*)din[5];
  const float* wihb0  = (const float*)din[6];
  const float* wihb12 = (const float*)din[7];
  const float* whhb   = (const float*)din[8];
  const float* bsb    = (const float*)din[9];

  char* p = ws;
  auto alloc = [&](size_t n){ char* r = p; p += (n + 255) & ~(size_t)255; return r; };
  GXT* gx            = (GXT*)alloc((size_t)T_*B_*NW*sizeof(GXT));
  unsigned short* xA = (unsigned short*)alloc((size_t)T_*B_*832*2);
  unsigned short* xB = (unsigned short*)alloc((size_t)T_*B_*832*2);
  unsigned short* wihp = (unsigned short*)alloc((size_t)NW*K12P*2);
  unsigned short* whhp = (unsigned short*)alloc((size_t)2*NTILES*128*424*2);
  float* biasp       = (float*)alloc((size_t)NW*4);
  unsigned short* hbuf = (unsigned short*)alloc((size_t)2*NGRP*2*16*HP*2);
  unsigned int* ctr  = (unsigned int*)alloc(256);

  hipMemsetAsync(out, 0, (size_t)T_*B_*800*4, stream);
  {
    size_t n = (size_t)T_*B_*K0P;
    k_conv_x0<<<dim3((unsigned)((n+255)/256)), dim3(256), 0, stream>>>(x, xA);
  }
  hipFuncSetAttribute(reinterpret_cast<const void*>(&lstm_rec<GXT,false>),
                      hipFuncAttributeMaxDynamicSharedMemorySize, LDS_TOTAL);
  hipFuncSetAttribute(reinterpret_cast<const void*>(&lstm_rec<GXT,true>),
                      hipFuncAttributeMaxDynamicSharedMemorySize, LDS_TOTAL);

  const unsigned short* xin[3] = {xA, xB, xA};
  unsigned short* xout[3] = {xB, xA, nullptr};
  const int ldas[3] = {K0P, 832, 832};
  const int Ks[3]   = {K0P, K12P, K12P};

  for (int lyr = 0; lyr < 3; ++lyr){
    const float* wf = (lyr == 0) ? wihf0 : wihf12 + (size_t)(lyr-1)*1600*800;
    const float* wb = (lyr == 0) ? wihb0 : wihb12 + (size_t)(lyr-1)*1600*800;
    {
      size_t n = (size_t)NW*Ks[lyr];
      k_prep_wih<<<dim3((unsigned)((n+255)/256)), dim3(256), 0, stream>>>(
          wf, wb, Ks[lyr], lyr ? 1 : 0, wihp);
    }
    k_prep_bias<<<dim3((NW+255)/256), dim3(256), 0, stream>>>(
        bsf + (size_t)lyr*1600, bsb + (size_t)lyr*1600, biasp);
    gemm_gx<GXT><<<dim3(26, 512), dim3(256), 0, stream>>>(
        xin[lyr], ldas[lyr], Ks[lyr], wihp, biasp, gx, lens);
    {
      size_t n = (size_t)2*NTILES*128*424;
      k_prep_whh<<<dim3((unsigned)((n+255)/256)), dim3(256), 0, stream>>>(
          whhf + (size_t)lyr*1600*400, whhb + (size_t)lyr*1600*400, whhp);
    }
    hipMemsetAsync(ctr, 0, 256, stream);

    const GXT* a_gx = gx;
    const unsigned short* a_whhp = whhp;
    const int* a_lens = lens;
    unsigned short* a_hbuf = hbuf;
    unsigned short* a_xn = xout[lyr];
    float* a_out = out;
    unsigned int* a_ctr = ctr;
    void* args[7] = {&a_gx, &a_whhp, &a_lens, &a_hbuf, &a_xn, &a_out, &a_ctr};
    if (lyr < 2)
      hipLaunchCooperativeKernel(reinterpret_cast<const void*>(&lstm_rec<GXT,false>),
                                 dim3(REC_BLOCKS), dim3(256), args, LDS_TOTAL, stream);
    else
      hipLaunchCooperativeKernel(reinterpret_cast<const void*>(&lstm_rec<GXT,true>),
                                 dim3(REC_BLOCKS), dim3(256), args, LDS_TOTAL, stream);
  }
}

extern "C" void kernel_launch(void* const* d_in, const int* in_sizes, int n_in,
                              void* d_out, int out_size, void* d_ws, size_t ws_size,
                              hipStream_t stream)
{
  (void)in_sizes; (void)n_in; (void)out_size;
  auto align = [](size_t n){ return (n + 255) & ~(size_t)255; };
  const size_t fixed =
      align((size_t)T_*B_*832*2) * 2 +
      align((size_t)NW*K12P*2) +
      align((size_t)2*NTILES*128*424*2) +
      align((size_t)NW*4) +
      align((size_t)2*NGRP*2*16*HP*2) + 256;
  const size_t need32 = align((size_t)T_*B_*NW*4) + fixed;
  const size_t need16 = align((size_t)T_*B_*NW*2) + fixed;

  if (ws_size >= need32)
    run_all<float>(d_in, (float*)d_out, (char*)d_ws, stream);
  else if (ws_size >= need16)
    run_all<unsigned short>(d_in, (float*)d_out, (char*)d_ws, stream);
  else
    hipMemsetAsync(d_out, 0, (size_t)T_*B_*800*4, stream);
}

// Round 3
// 8937.189 us; speedup vs baseline: 5.5544x; 5.5544x over previous
//
#include <hip/hip_runtime.h>
#include <stdint.h>
#include <stddef.h>

#define T_ 512
#define B_ 128
#define D_ 400
#define H_ 400
#define HP 416
#define GP 1664            // 4*HP (per-dir padded gate dim)
#define NW 3328            // both dirs stacked
#define K0P 448            // padded K for layer 0 GEMM
#define K12P 832           // padded K for layers 1,2 GEMM
#define NTILES 13          // h tiles of 32 per dir
#define NGRP 8             // batch groups of 16
#define REC_BLOCKS 208     // 2*8*13

// ---- recurrent-kernel LDS layout (bytes) ----
#define WHH_BYTES (128*424*2)            // 108544
#define HS_OFF    WHH_BYTES
#define HS_BYTES  (16*424*2)             // 13568
#define GC_OFF    (HS_OFF + HS_BYTES)    // 122112
#define GC_FSTRIDE 576                   // floats per gate region (16*36)
#define GC_BYTES  (4*GC_FSTRIDE*4)       // 9216
#define GXS_OFF   (GC_OFF + GC_BYTES)    // 131328
#define GXS_BYTES (16*132*4)             // 8448
#define LDS_TOTAL (GXS_OFF + GXS_BYTES)  // 139776

typedef __attribute__((ext_vector_type(8))) __bf16 bf16x8;
typedef __attribute__((ext_vector_type(4))) float f32x4;
typedef __attribute__((ext_vector_type(8))) unsigned short us8;

__device__ __forceinline__ unsigned short f2bf(float f){
  unsigned u = __builtin_bit_cast(unsigned, f);
  u = (u + 0x7FFFu + ((u >> 16) & 1u)) >> 16;
  return (unsigned short)u;
}
__device__ __forceinline__ float bf2f(unsigned short s){
  unsigned u = ((unsigned)s) << 16;
  return __builtin_bit_cast(float, u);
}
__device__ __forceinline__ float sigm(float x){ return 1.f / (1.f + __expf(-x)); }
__device__ __forceinline__ float tanh_f(float x){
  float ax = fabsf(x);
  float e = __expf(-2.f * ax);
  float t = (1.f - e) / (1.f + e);
  return x < 0.f ? -t : t;
}
__device__ __forceinline__ void store_gx(float* p, float v){ *p = v; }
__device__ __forceinline__ void store_gx(unsigned short* p, float v){ *p = f2bf(v); }

// agent-scope relaxed atomics == MALL-coherent accesses, NO cache maintenance
__device__ __forceinline__ void h_store_u32(unsigned* p, unsigned v){
  __hip_atomic_store(p, v, __ATOMIC_RELAXED, __HIP_MEMORY_SCOPE_AGENT);
}
__device__ __forceinline__ unsigned long long h_load_u64(const unsigned long long* p){
  return __hip_atomic_load(p, __ATOMIC_RELAXED, __HIP_MEMORY_SCOPE_AGENT);
}

// ======================= prep kernels =======================
__global__ void k_conv_x0(const float* __restrict__ x, unsigned short* __restrict__ xa){
  const size_t i = (size_t)blockIdx.x*256 + threadIdx.x;
  if (i >= (size_t)T_*B_*K0P) return;
  const int k = (int)(i % K0P);
  const size_t tb = i / K0P;
  xa[i] = f2bf(k < D_ ? x[tb*D_ + k] : 0.f);
}

__global__ void k_prep_wih(const float* __restrict__ wf, const float* __restrict__ wb,
                           int K, int mode, unsigned short* __restrict__ dst){
  const size_t i = (size_t)blockIdx.x*256 + threadIdx.x;
  if (i >= (size_t)NW*K) return;
  const int k = (int)(i % K);
  const int n = (int)(i / K);
  const int d = n / GP, ng = n % GP, g = ng / HP, r = ng % HP;
  const float* Wsrc = d ? wb : wf;
  float v = 0.f;
  if (r < H_){
    if (mode == 0){                       // layer 0: K real 400
      if (k < D_) v = Wsrc[(size_t)(g*H_ + r)*D_ + k];
    } else {                              // layers 1,2: [fwd400|pad16|bwd400|pad16]
      int ks = (k < 400) ? k : ((k >= 416 && k < 816) ? (k - 16) : -1);
      if (ks >= 0) v = Wsrc[(size_t)(g*H_ + r)*800 + ks];
    }
  }
  dst[i] = f2bf(v);
}

__global__ void k_prep_whh(const float* __restrict__ wf, const float* __restrict__ wb,
                           unsigned short* __restrict__ dst){
  const size_t i = (size_t)blockIdx.x*256 + threadIdx.x;
  if (i >= (size_t)2*NTILES*128*424) return;
  const int k = (int)(i % 424);
  size_t r1 = i / 424;
  const int nloc = (int)(r1 % 128);
  size_t r2 = r1 / 128;
  const int tile = (int)(r2 % NTILES);
  const int d = (int)(r2 / NTILES);
  const int g = nloc >> 5, rr = nloc & 31;
  const int c = tile*32 + rr;
  const float* Wsrc = d ? wb : wf;
  float v = (c < H_ && k < H_) ? Wsrc[(size_t)(g*H_ + c)*H_ + k] : 0.f;
  dst[i] = f2bf(v);
}

__global__ void k_prep_bias(const float* __restrict__ bsf, const float* __restrict__ bsb,
                            float* __restrict__ dst){
  const int n = blockIdx.x*256 + threadIdx.x;
  if (n >= NW) return;
  const int d = n / GP, ng = n % GP, g = ng / HP, r = ng % HP;
  dst[n] = (r < H_) ? (d ? bsb : bsf)[g*H_ + r] : 0.f;
}

// ======================= gx GEMM =======================
template<typename GXT>
__global__ __launch_bounds__(256) void gemm_gx(
    const unsigned short* __restrict__ X, int lda, int K,
    const unsigned short* __restrict__ W,
    const float* __restrict__ bias,
    GXT* __restrict__ gx,
    const int* __restrict__ lens)
{
  const int t = blockIdx.y;
  if (t >= lens[0]) return;                 // gx at t >= max_len is never read
  const int n0 = blockIdx.x * 128;
  __shared__ unsigned short As[128*64];
  __shared__ unsigned short Bs[128*64];
  const int tid = threadIdx.x;
  const int l = tid & 63;
  const int w = tid >> 6;
  const int wm = (w >> 1) * 64, wn = (w & 1) * 64;
  const int lr = l & 15, lk = l >> 4;
  f32x4 acc[4][4];
  #pragma unroll
  for (int i = 0; i < 4; ++i)
    #pragma unroll
    for (int j = 0; j < 4; ++j) acc[i][j] = (f32x4){0.f,0.f,0.f,0.f};

  const unsigned short* Xb = X + (size_t)t * B_ * lda;
  const int r_ = tid >> 3, s_ = (tid & 7) * 8;

  for (int k0 = 0; k0 < K; k0 += 64){
    us8 va[4], vb[4];
    #pragma unroll
    for (int i = 0; i < 4; ++i){
      const int r = i*32 + r_;
      va[i] = *(const us8*)(Xb + (size_t)r*lda + k0 + s_);
      vb[i] = *(const us8*)(W  + (size_t)(n0 + r)*K + k0 + s_);
    }
    __syncthreads();
    #pragma unroll
    for (int i = 0; i < 4; ++i){
      const int r = i*32 + r_;
      *(us8*)&As[r*64 + s_] = va[i];
      *(us8*)&Bs[r*64 + s_] = vb[i];
    }
    __syncthreads();
    #pragma unroll
    for (int kk = 0; kk < 2; ++kk){
      bf16x8 af[4], bfr[4];
      #pragma unroll
      for (int mi = 0; mi < 4; ++mi)
        af[mi] = __builtin_bit_cast(bf16x8, *(const us8*)&As[(wm + mi*16 + lr)*64 + kk*32 + lk*8]);
      #pragma unroll
      for (int ni = 0; ni < 4; ++ni)
        bfr[ni] = __builtin_bit_cast(bf16x8, *(const us8*)&Bs[(wn + ni*16 + lr)*64 + kk*32 + lk*8]);
      #pragma unroll
      for (int mi = 0; mi < 4; ++mi)
        #pragma unroll
        for (int ni = 0; ni < 4; ++ni)
          acc[mi][ni] = __builtin_amdgcn_mfma_f32_16x16x32_bf16(af[mi], bfr[ni], acc[mi][ni], 0, 0, 0);
    }
  }
  #pragma unroll
  for (int ni = 0; ni < 4; ++ni){
    const int col = n0 + wn + ni*16 + lr;
    const float bv = bias[col];
    #pragma unroll
    for (int mi = 0; mi < 4; ++mi){
      #pragma unroll
      for (int r = 0; r < 4; ++r){
        const int b = wm + mi*16 + lk*4 + r;
        store_gx(gx + ((size_t)t*B_ + b)*NW + col, acc[mi][ni][r] + bv);
      }
    }
  }
}

// ======================= recurrent (cooperative) =======================
// grid: 208 blocks = dir(2) x group(8 of 16 batches) x htile(13 of 32 cols)
// wave w (of 4) owns gate w. Per-group 13-block monotonic counter per step.
// All cross-block data (hbuf, ctr) uses agent-scope RELAXED atomics
// (MALL-coherent) -> no buffer_wbl2 / buffer_inv in the loop.
template<typename GXT, bool LAST>
__global__ __launch_bounds__(256) void lstm_rec(
    const GXT* __restrict__ gx,
    const unsigned short* __restrict__ whhp,   // [2][13][128][424] bf16
    const int* __restrict__ lens,
    unsigned short* hbuf,                      // [2*8][2][16][416] bf16 (host-zeroed)
    unsigned short* xn,                        // [T][128][832] bf16 (or unused)
    float* out,                                // [T][128][800] f32 (or unused)
    unsigned int* ctr)                         // [16] at 64-uint spacing (host-zeroed)
{
  extern __shared__ char smem[];
  unsigned short* WhhL = (unsigned short*)smem;
  unsigned short* HS   = (unsigned short*)(smem + HS_OFF);
  float* GC  = (float*)(smem + GC_OFF);
  float* GXS = (float*)(smem + GXS_OFF);

  const int tid = threadIdx.x;
  const int bid = blockIdx.x;
  const int dir  = bid / 104;
  const int rem  = bid % 104;
  const int grp  = rem / NTILES;
  const int tile = rem % NTILES;
  const int l  = tid & 63;
  const int w  = tid >> 6;
  const int lr = l & 15;
  const int lk = l >> 4;
  const int cid = dir*NGRP + grp;
  unsigned int* myctr = ctr + cid*64;

  // Whh blob -> LDS (resident for whole kernel)
  {
    const unsigned short* src = whhp + (size_t)(dir*NTILES + tile) * (128*424);
    for (int i = tid; i < (128*424)/8; i += 256)
      *(us8*)&WhhL[i*8] = *(const us8*)(src + (size_t)i*8);
  }
  const size_t hgrp = (size_t)cid * 2 * 16 * HP;
  const int grp_len = lens[grp*16];          // lens sorted desc -> group max
  const int eb  = tid & 15;                  // elementwise batch
  const int p2  = tid >> 4;                  // col pair index: cols {2*p2, 2*p2+1}
  const int mylen = lens[grp*16 + eb];
  float cs0 = 0.f, cs1 = 0.f, hs0 = 0.f, hs1 = 0.f;
  __syncthreads();

  int epoch = 1, par = 0;
  const int pb = tid >> 4, q = tid & 15, qg = q >> 2, qj = (q & 3) * 8;

  for (int s = 0; s < T_; ++s){
    const int t = dir ? (T_ - 1 - s) : s;
    if (t >= grp_len) continue;            // whole group idle: uniform, no barrier

    // prefetch gx for this step (independent of the handshake)
    f32x4 pfa, pfb;
    {
      const size_t goff = ((size_t)t*B_ + grp*16 + pb) * NW + (size_t)dir*GP + qg*HP + tile*32 + qj;
      if constexpr (sizeof(GXT) == 4){
        const float* gp = (const float*)gx + goff;
        pfa = *(const f32x4*)gp;
        pfb = *(const f32x4*)(gp + 4);
      } else {
        us8 v = *(const us8*)((const unsigned short*)gx + goff);
        pfa = (f32x4){bf2f(v[0]), bf2f(v[1]), bf2f(v[2]), bf2f(v[3])};
        pfb = (f32x4){bf2f(v[4]), bf2f(v[5]), bf2f(v[6]), bf2f(v[7])};
      }
    }
    // wait for all 13 blocks of this group to have published h of previous step
    {
      const unsigned tgt = 13u * (unsigned)(epoch - 1);
      if (tid == 0 && tgt){
        while (__hip_atomic_load(myctr, __ATOMIC_RELAXED, __HIP_MEMORY_SCOPE_AGENT) < tgt)
          __builtin_amdgcn_s_sleep(1);
      }
      __syncthreads();
    }

    // stage h (16 x 416) -> LDS via MALL-coherent 8B loads, padded stride 424
    {
      const unsigned long long* hsrc =
          (const unsigned long long*)(hbuf + hgrp + (size_t)par*16*HP);
      for (int i = tid; i < 1664; i += 256){     // 16 batches x 104 qwords
        int b = i / 104, sg = i % 104;
        unsigned long long v = h_load_u64(hsrc + (size_t)b*104 /*416 shorts = 104 u64*/ + sg);
        *(unsigned long long*)&HS[b*424 + sg*4] = v;
      }
    }
    __syncthreads();

    // gates[16 x 32] for gate w:  h(16x416) @ Whh_tile^T
    f32x4 a0 = (f32x4){0.f,0.f,0.f,0.f}, a1 = (f32x4){0.f,0.f,0.f,0.f};
    {
      const int ab  = lr*424 + lk*8;
      const int nb0 = (w*32 + lr)*424 + lk*8;
      const int nb1 = nb0 + 16*424;
      #pragma unroll
      for (int kk = 0; kk < 13; ++kk){
        bf16x8 av = __builtin_bit_cast(bf16x8, *(const us8*)&HS[ab + kk*32]);
        bf16x8 b0 = __builtin_bit_cast(bf16x8, *(const us8*)&WhhL[nb0 + kk*32]);
        bf16x8 b1 = __builtin_bit_cast(bf16x8, *(const us8*)&WhhL[nb1 + kk*32]);
        a0 = __builtin_amdgcn_mfma_f32_16x16x32_bf16(av, b0, a0, 0, 0, 0);
        a1 = __builtin_amdgcn_mfma_f32_16x16x32_bf16(av, b1, a1, 0, 0, 0);
      }
    }
    // publish gate partials + gx to LDS
    {
      float* Gw = GC + w * GC_FSTRIDE;
      #pragma unroll
      for (int r = 0; r < 4; ++r){
        Gw[(lk*4 + r)*36 + lr]      = a0[r];
        Gw[(lk*4 + r)*36 + 16 + lr] = a1[r];
      }
      float* gp = GXS + pb*132 + qg*32 + qj;
      *(f32x4*)gp = pfa;
      *(f32x4*)(gp + 4) = pfb;
    }
    __syncthreads();

    // elementwise LSTM cell: thread owns (b=eb, cols {2*p2, 2*p2+1})
    const bool act = t < mylen;
    const int c0 = 2*p2, c1 = 2*p2 + 1;
    {
      const float gi0 = GC[0*GC_FSTRIDE + eb*36 + c0] + GXS[eb*132 + c0];
      const float gf0 = GC[1*GC_FSTRIDE + eb*36 + c0] + GXS[eb*132 + 32 + c0];
      const float gg0 = GC[2*GC_FSTRIDE + eb*36 + c0] + GXS[eb*132 + 64 + c0];
      const float go0 = GC[3*GC_FSTRIDE + eb*36 + c0] + GXS[eb*132 + 96 + c0];
      const float gi1 = GC[0*GC_FSTRIDE + eb*36 + c1] + GXS[eb*132 + c1];
      const float gf1 = GC[1*GC_FSTRIDE + eb*36 + c1] + GXS[eb*132 + 32 + c1];
      const float gg1 = GC[2*GC_FSTRIDE + eb*36 + c1] + GXS[eb*132 + 64 + c1];
      const float go1 = GC[3*GC_FSTRIDE + eb*36 + c1] + GXS[eb*132 + 96 + c1];
      const float cn0 = sigm(gf0)*cs0 + sigm(gi0)*tanh_f(gg0);
      const float hn0 = sigm(go0) * tanh_f(cn0);
      const float cn1 = sigm(gf1)*cs1 + sigm(gi1)*tanh_f(gg1);
      const float hn1 = sigm(go1) * tanh_f(cn1);
      if (act){ cs0 = cn0; hs0 = hn0; cs1 = cn1; hs1 = hn1; }
    }
    // publish h (frozen value if masked) into next parity buffer: packed 4B
    const unsigned hu = (unsigned)f2bf(hs0) | ((unsigned)f2bf(hs1) << 16);
    h_store_u32((unsigned*)(hbuf + hgrp + (size_t)(par^1)*16*HP + (size_t)eb*HP + tile*32 + c0), hu);
    if (act){
      const int bg = grp*16 + eb;
      const int hc = tile*32 + c0;
      if constexpr (LAST){
        float* op = out + ((size_t)t*B_ + bg)*800 + dir*H_ + hc;
        if (hc < H_)     op[0] = hs0;
        if (hc + 1 < H_) op[1] = hs1;
      } else {
        *(unsigned*)(xn + ((size_t)t*B_ + bg)*832 + (size_t)dir*HP + hc) = hu;
      }
    }
    asm volatile("s_waitcnt vmcnt(0)" ::: "memory");   // h stores MALL-visible
    __syncthreads();                                   // ...for ALL waves
    if (tid == 0)
      __hip_atomic_fetch_add(myctr, 1u, __ATOMIC_RELAXED, __HIP_MEMORY_SCOPE_AGENT);
    ++epoch; par ^= 1;
  }
}

// ======================= host side =======================
template<typename GXT>
static void run_all(void* const* din, float* out, char* ws, hipStream_t stream)
{
  const float* x      = (const float*)din[0];
  const int* lens     = (const int*)din[1];
  const float* wihf0  = (const float*)din[2];
  const float* wihf12 = (const float*)din[3];
  const float* whhf   = (const float*)din[4];
  const float* bsf    = (const float*)din[5];
  const float* wihb0  = (const float*)din[6];
  const float* wihb12 = (const float*)din[7];
  const float* whhb   = (const float*)din[8];
  const float* bsb    = (const float*)din[9];

  char* p = ws;
  auto alloc = [&](size_t n){ char* r = p; p += (n + 255) & ~(size_t)255; return r; };
  GXT* gx            = (GXT*)alloc((size_t)T_*B_*NW*sizeof(GXT));
  unsigned short* xA = (unsigned short*)alloc((size_t)T_*B_*832*2);
  unsigned short* xB = (unsigned short*)alloc((size_t)T_*B_*832*2);
  unsigned short* wihp = (unsigned short*)alloc((size_t)NW*K12P*2);
  unsigned short* whhp = (unsigned short*)alloc((size_t)2*NTILES*128*424*2);
  float* biasp       = (float*)alloc((size_t)NW*4);
  unsigned short* hbuf = (unsigned short*)alloc((size_t)2*NGRP*2*16*HP*2);
  unsigned int* ctr  = (unsigned int*)alloc(16*64*4);

  hipMemsetAsync(out, 0, (size_t)T_*B_*800*4, stream);
  {
    size_t n = (size_t)T_*B_*K0P;
    k_conv_x0<<<dim3((unsigned)((n+255)/256)), dim3(256), 0, stream>>>(x, xA);
  }
  hipFuncSetAttribute(reinterpret_cast<const void*>(&lstm_rec<GXT,false>),
                      hipFuncAttributeMaxDynamicSharedMemorySize, LDS_TOTAL);
  hipFuncSetAttribute(reinterpret_cast<const void*>(&lstm_rec<GXT,true>),
                      hipFuncAttributeMaxDynamicSharedMemorySize, LDS_TOTAL);

  const unsigned short* xin[3] = {xA, xB, xA};
  unsigned short* xout[3] = {xB, xA, nullptr};
  const int ldas[3] = {K0P, 832, 832};
  const int Ks[3]   = {K0P, K12P, K12P};

  for (int lyr = 0; lyr < 3; ++lyr){
    const float* wf = (lyr == 0) ? wihf0 : wihf12 + (size_t)(lyr-1)*1600*800;
    const float* wb = (lyr == 0) ? wihb0 : wihb12 + (size_t)(lyr-1)*1600*800;
    {
      size_t n = (size_t)NW*Ks[lyr];
      k_prep_wih<<<dim3((unsigned)((n+255)/256)), dim3(256), 0, stream>>>(
          wf, wb, Ks[lyr], lyr ? 1 : 0, wihp);
    }
    k_prep_bias<<<dim3((NW+255)/256), dim3(256), 0, stream>>>(
        bsf + (size_t)lyr*1600, bsb + (size_t)lyr*1600, biasp);
    gemm_gx<GXT><<<dim3(26, 512), dim3(256), 0, stream>>>(
        xin[lyr], ldas[lyr], Ks[lyr], wihp, biasp, gx, lens);
    {
      size_t n = (size_t)2*NTILES*128*424;
      k_prep_whh<<<dim3((unsigned)((n+255)/256)), dim3(256), 0, stream>>>(
          whhf + (size_t)lyr*1600*400, whhb + (size_t)lyr*1600*400, whhp);
    }
    hipMemsetAsync(ctr, 0, 16*64*4, stream);
    hipMemsetAsync(hbuf, 0, (size_t)2*NGRP*2*16*HP*2, stream);

    const GXT* a_gx = gx;
    const unsigned short* a_whhp = whhp;
    const int* a_lens = lens;
    unsigned short* a_hbuf = hbuf;
    unsigned short* a_xn = xout[lyr];
    float* a_out = out;
    unsigned int* a_ctr = ctr;
    void* args[7] = {&a_gx, &a_whhp, &a_lens, &a_hbuf, &a_xn, &a_out, &a_ctr};
    if (lyr < 2)
      hipLaunchCooperativeKernel(reinterpret_cast<const void*>(&lstm_rec<GXT,false>),
                                 dim3(REC_BLOCKS), dim3(256), args, LDS_TOTAL, stream);
    else
      hipLaunchCooperativeKernel(reinterpret_cast<const void*>(&lstm_rec<GXT,true>),
                                 dim3(REC_BLOCKS), dim3(256), args, LDS_TOTAL, stream);
  }
}

extern "C" void kernel_launch(void* const* d_in, const int* in_sizes, int n_in,
                              void* d_out, int out_size, void* d_ws, size_t ws_size,
                              hipStream_t stream)
{
  (void)in_sizes; (void)n_in; (void)out_size;
  auto align = [](size_t n){ return (n + 255) & ~(size_t)255; };
  const size_t fixed =
      align((size_t)T_*B_*832*2) * 2 +
      align((size_t)NW*K12P*2) +
      align((size_t)2*NTILES*128*424*2) +
      align((size_t)NW*4) +
      align((size_t)2*NGRP*2*16*HP*2) + align(16*64*4);
  const size_t need32 = align((size_t)T_*B_*NW*4) + fixed;
  const size_t need16 = align((size_t)T_*B_*NW*2) + fixed;

  if (ws_size >= need32)
    run_all<float>(d_in, (float*)d_out, (char*)d_ws, stream);
  else if (ws_size >= need16)
    run_all<unsigned short>(d_in, (float*)d_out, (char*)d_ws, stream);
  else
    hipMemsetAsync(d_out, 0, (size_t)T_*B_*800*4, stream);
}

// Round 4
// 6696.367 us; speedup vs baseline: 7.4131x; 1.3346x over previous
//
#include <hip/hip_runtime.h>
#include <stdint.h>
#include <stddef.h>

#define T_ 512
#define B_ 128
#define D_ 400
#define H_ 400
#define HP 416
#define GP 1664            // 4*HP (per-dir padded gate dim)
#define NW 3328            // both dirs stacked
#define K0P 448            // padded K for layer 0 GEMM
#define K12P 832           // padded K for layers 1,2 GEMM
#define NTILES 13          // h tiles of 32 per dir
#define NGRP 8             // batch groups of 16
#define REC_BLOCKS 208     // 2*8*13
#define PAIRS 208          // 416 cols / 2 per batch row (u64 slots)

// ---- recurrent-kernel LDS layout (bytes) ----
#define WHH_BYTES (128*424*2)            // 108544
#define HS_OFF    WHH_BYTES
#define HS_BYTES  (16*424*2)             // 13568
#define GC_OFF    (HS_OFF + HS_BYTES)    // 122112
#define GC_FSTRIDE 576                   // floats per gate region (16*36)
#define GC_BYTES  (4*GC_FSTRIDE*4)       // 9216
#define GXS_OFF   (GC_OFF + GC_BYTES)    // 131328
#define GXS_BYTES (16*132*4)             // 8448
#define LDS_TOTAL (GXS_OFF + GXS_BYTES)  // 139776

// tagged h buffer: [16 cid][2 parity][16 batch][208 pair] u64
#define HBT_U64   ((size_t)16*2*16*PAIRS)
#define HBT_BYTES (HBT_U64*8)            // 851968

typedef __attribute__((ext_vector_type(8))) __bf16 bf16x8;
typedef __attribute__((ext_vector_type(4))) float f32x4;
typedef __attribute__((ext_vector_type(8))) unsigned short us8;

__device__ __forceinline__ unsigned short f2bf(float f){
  unsigned u = __builtin_bit_cast(unsigned, f);
  u = (u + 0x7FFFu + ((u >> 16) & 1u)) >> 16;
  return (unsigned short)u;
}
__device__ __forceinline__ float bf2f(unsigned short s){
  unsigned u = ((unsigned)s) << 16;
  return __builtin_bit_cast(float, u);
}
__device__ __forceinline__ float sigm(float x){ return 1.f / (1.f + __expf(-x)); }
__device__ __forceinline__ float tanh_f(float x){
  float ax = fabsf(x);
  float e = __expf(-2.f * ax);
  float t = (1.f - e) / (1.f + e);
  return x < 0.f ? -t : t;
}
__device__ __forceinline__ void store_gx(float* p, float v){ *p = v; }
__device__ __forceinline__ void store_gx(unsigned short* p, float v){ *p = f2bf(v); }

// agent-scope relaxed atomics == MALL-coherent accesses, NO cache maintenance
__device__ __forceinline__ void h_store_u64(unsigned long long* p, unsigned long long v){
  __hip_atomic_store(p, v, __ATOMIC_RELAXED, __HIP_MEMORY_SCOPE_AGENT);
}
__device__ __forceinline__ unsigned long long h_load_u64(const unsigned long long* p){
  return __hip_atomic_load(p, __ATOMIC_RELAXED, __HIP_MEMORY_SCOPE_AGENT);
}

// ======================= prep kernels =======================
__global__ void k_conv_x0(const float* __restrict__ x, unsigned short* __restrict__ xa){
  const size_t i = (size_t)blockIdx.x*256 + threadIdx.x;
  if (i >= (size_t)T_*B_*K0P) return;
  const int k = (int)(i % K0P);
  const size_t tb = i / K0P;
  xa[i] = f2bf(k < D_ ? x[tb*D_ + k] : 0.f);
}

__global__ void k_prep_wih(const float* __restrict__ wf, const float* __restrict__ wb,
                           int K, int mode, unsigned short* __restrict__ dst){
  const size_t i = (size_t)blockIdx.x*256 + threadIdx.x;
  if (i >= (size_t)NW*K) return;
  const int k = (int)(i % K);
  const int n = (int)(i / K);
  const int d = n / GP, ng = n % GP, g = ng / HP, r = ng % HP;
  const float* Wsrc = d ? wb : wf;
  float v = 0.f;
  if (r < H_){
    if (mode == 0){                       // layer 0: K real 400
      if (k < D_) v = Wsrc[(size_t)(g*H_ + r)*D_ + k];
    } else {                              // layers 1,2: [fwd400|pad16|bwd400|pad16]
      int ks = (k < 400) ? k : ((k >= 416 && k < 816) ? (k - 16) : -1);
      if (ks >= 0) v = Wsrc[(size_t)(g*H_ + r)*800 + ks];
    }
  }
  dst[i] = f2bf(v);
}

__global__ void k_prep_whh(const float* __restrict__ wf, const float* __restrict__ wb,
                           unsigned short* __restrict__ dst){
  const size_t i = (size_t)blockIdx.x*256 + threadIdx.x;
  if (i >= (size_t)2*NTILES*128*424) return;
  const int k = (int)(i % 424);
  size_t r1 = i / 424;
  const int nloc = (int)(r1 % 128);
  size_t r2 = r1 / 128;
  const int tile = (int)(r2 % NTILES);
  const int d = (int)(r2 / NTILES);
  const int g = nloc >> 5, rr = nloc & 31;
  const int c = tile*32 + rr;
  const float* Wsrc = d ? wb : wf;
  float v = (c < H_ && k < H_) ? Wsrc[(size_t)(g*H_ + c)*H_ + k] : 0.f;
  dst[i] = f2bf(v);
}

__global__ void k_prep_bias(const float* __restrict__ bsf, const float* __restrict__ bsb,
                            float* __restrict__ dst){
  const int n = blockIdx.x*256 + threadIdx.x;
  if (n >= NW) return;
  const int d = n / GP, ng = n % GP, g = ng / HP, r = ng % HP;
  dst[n] = (r < H_) ? (d ? bsb : bsf)[g*H_ + r] : 0.f;
}

// ======================= gx GEMM =======================
template<typename GXT>
__global__ __launch_bounds__(256) void gemm_gx(
    const unsigned short* __restrict__ X, int lda, int K,
    const unsigned short* __restrict__ W,
    const float* __restrict__ bias,
    GXT* __restrict__ gx,
    const int* __restrict__ lens)
{
  const int t = blockIdx.y;
  if (t >= lens[0]) return;                 // gx at t >= max_len is never read
  const int n0 = blockIdx.x * 128;
  __shared__ unsigned short As[128*64];
  __shared__ unsigned short Bs[128*64];
  const int tid = threadIdx.x;
  const int l = tid & 63;
  const int w = tid >> 6;
  const int wm = (w >> 1) * 64, wn = (w & 1) * 64;
  const int lr = l & 15, lk = l >> 4;
  f32x4 acc[4][4];
  #pragma unroll
  for (int i = 0; i < 4; ++i)
    #pragma unroll
    for (int j = 0; j < 4; ++j) acc[i][j] = (f32x4){0.f,0.f,0.f,0.f};

  const unsigned short* Xb = X + (size_t)t * B_ * lda;
  const int r_ = tid >> 3, s_ = (tid & 7) * 8;

  for (int k0 = 0; k0 < K; k0 += 64){
    us8 va[4], vb[4];
    #pragma unroll
    for (int i = 0; i < 4; ++i){
      const int r = i*32 + r_;
      va[i] = *(const us8*)(Xb + (size_t)r*lda + k0 + s_);
      vb[i] = *(const us8*)(W  + (size_t)(n0 + r)*K + k0 + s_);
    }
    __syncthreads();
    #pragma unroll
    for (int i = 0; i < 4; ++i){
      const int r = i*32 + r_;
      *(us8*)&As[r*64 + s_] = va[i];
      *(us8*)&Bs[r*64 + s_] = vb[i];
    }
    __syncthreads();
    #pragma unroll
    for (int kk = 0; kk < 2; ++kk){
      bf16x8 af[4], bfr[4];
      #pragma unroll
      for (int mi = 0; mi < 4; ++mi)
        af[mi] = __builtin_bit_cast(bf16x8, *(const us8*)&As[(wm + mi*16 + lr)*64 + kk*32 + lk*8]);
      #pragma unroll
      for (int ni = 0; ni < 4; ++ni)
        bfr[ni] = __builtin_bit_cast(bf16x8, *(const us8*)&Bs[(wn + ni*16 + lr)*64 + kk*32 + lk*8]);
      #pragma unroll
      for (int mi = 0; mi < 4; ++mi)
        #pragma unroll
        for (int ni = 0; ni < 4; ++ni)
          acc[mi][ni] = __builtin_amdgcn_mfma_f32_16x16x32_bf16(af[mi], bfr[ni], acc[mi][ni], 0, 0, 0);
    }
  }
  #pragma unroll
  for (int ni = 0; ni < 4; ++ni){
    const int col = n0 + wn + ni*16 + lr;
    const float bv = bias[col];
    #pragma unroll
    for (int mi = 0; mi < 4; ++mi){
      #pragma unroll
      for (int r = 0; r < 4; ++r){
        const int b = wm + mi*16 + lk*4 + r;
        store_gx(gx + ((size_t)t*B_ + b)*NW + col, acc[mi][ni][r] + bv);
      }
    }
  }
}

// ======================= recurrent (cooperative) =======================
// grid: 208 blocks = dir(2) x group(8 of 16 batches) x htile(13 of 32 cols)
// wave w (of 4) owns gate w. Synchronization is embedded in the data:
// each h pair is an atomic u64 {2x bf16, 32-bit step tag}. Producers
// fire-and-forget; consumers retry stale lines. No counters, no fences,
// no store-ack waits. Safe because a slot with tag k is only overwritten
// with tag k+2, which transitively requires all consumers of k done.
template<typename GXT, bool LAST>
__global__ __launch_bounds__(256) void lstm_rec(
    const GXT* __restrict__ gx,
    const unsigned short* __restrict__ whhp,   // [2][13][128][424] bf16
    const int* __restrict__ lens,
    unsigned long long* hbt,                   // tagged h (host-zeroed)
    unsigned short* xn,                        // [T][128][832] bf16 (or unused)
    float* out)                                // [T][128][800] f32 (or unused)
{
  extern __shared__ char smem[];
  unsigned short* WhhL = (unsigned short*)smem;
  unsigned short* HS   = (unsigned short*)(smem + HS_OFF);
  float* GC  = (float*)(smem + GC_OFF);
  float* GXS = (float*)(smem + GXS_OFF);

  const int tid = threadIdx.x;
  const int bid = blockIdx.x;
  const int dir  = bid / 104;
  const int rem  = bid % 104;
  const int grp  = rem / NTILES;
  const int tile = rem % NTILES;
  const int l  = tid & 63;
  const int w  = tid >> 6;
  const int lr = l & 15;
  const int lk = l >> 4;
  const int cid = dir*NGRP + grp;

  // Whh blob -> LDS (resident for whole kernel)
  {
    const unsigned short* src = whhp + (size_t)(dir*NTILES + tile) * (128*424);
    for (int i = tid; i < (128*424)/8; i += 256)
      *(us8*)&WhhL[i*8] = *(const us8*)(src + (size_t)i*8);
  }
  const int grp_len = lens[grp*16];          // lens sorted desc -> group max
  const int eb  = tid & 15;                  // elementwise batch
  const int p2  = tid >> 4;                  // col pair within tile
  const int mylen = lens[grp*16 + eb];
  float cs0 = 0.f, cs1 = 0.f, hs0 = 0.f, hs1 = 0.f;
  __syncthreads();

  int s_a = 0;                               // active-step counter (group-uniform)
  const int pb = tid >> 4, q = tid & 15, qg = q >> 2, qj = (q & 3) * 8;
  // this thread's h-publish slot (within-group part varies by parity only)
  unsigned long long* const myslot =
      hbt + (((size_t)cid*2)*16 + eb)*PAIRS + tile*16 + p2;

  for (int s = 0; s < T_; ++s){
    const int t = dir ? (T_ - 1 - s) : s;
    if (t >= grp_len) continue;            // whole group idle: uniform skip

    // prefetch gx for this step (in flight during tag-wait)
    f32x4 pfa, pfb;
    {
      const size_t goff = ((size_t)t*B_ + grp*16 + pb) * NW + (size_t)dir*GP + qg*HP + tile*32 + qj;
      if constexpr (sizeof(GXT) == 4){
        const float* gp = (const float*)gx + goff;
        pfa = *(const f32x4*)gp;
        pfb = *(const f32x4*)(gp + 4);
      } else {
        us8 v = *(const us8*)((const unsigned short*)gx + goff);
        pfa = (f32x4){bf2f(v[0]), bf2f(v[1]), bf2f(v[2]), bf2f(v[3])};
        pfb = (f32x4){bf2f(v[4]), bf2f(v[5]), bf2f(v[6]), bf2f(v[7])};
      }
    }

    // ---- stage h (16x416) -> LDS with per-line tag validation ----
    {
      const unsigned rtag = (unsigned)s_a;
      const unsigned long long* hb =
          hbt + ((size_t)(cid*2 + (s_a & 1))*16)*PAIRS;   // [16][208] linear
      unsigned long long v[13];
      #pragma unroll
      for (int j = 0; j < 13; ++j)
        v[j] = h_load_u64(hb + j*256 + tid);
      unsigned stale = 0;
      #pragma unroll
      for (int j = 0; j < 13; ++j)
        if ((unsigned)(v[j] >> 32) != rtag) stale |= 1u << j;
      while (stale){
        const unsigned m = stale;
        #pragma unroll
        for (int j = 0; j < 13; ++j)
          if (m & (1u << j)) v[j] = h_load_u64(hb + j*256 + tid);
        #pragma unroll
        for (int j = 0; j < 13; ++j)
          if ((m & (1u << j)) && (unsigned)(v[j] >> 32) == rtag) stale &= ~(1u << j);
      }
      #pragma unroll
      for (int j = 0; j < 13; ++j){
        const int idx = j*256 + tid;
        const int b = idx / PAIRS, p = idx % PAIRS;
        *(unsigned*)&HS[b*424 + 2*p] = (unsigned)v[j];
      }
    }
    __syncthreads();

    // gates[16 x 32] for gate w:  h(16x416) @ Whh_tile^T
    f32x4 a0 = (f32x4){0.f,0.f,0.f,0.f}, a1 = (f32x4){0.f,0.f,0.f,0.f};
    {
      const int ab  = lr*424 + lk*8;
      const int nb0 = (w*32 + lr)*424 + lk*8;
      const int nb1 = nb0 + 16*424;
      #pragma unroll
      for (int kk = 0; kk < 13; ++kk){
        bf16x8 av = __builtin_bit_cast(bf16x8, *(const us8*)&HS[ab + kk*32]);
        bf16x8 b0 = __builtin_bit_cast(bf16x8, *(const us8*)&WhhL[nb0 + kk*32]);
        bf16x8 b1 = __builtin_bit_cast(bf16x8, *(const us8*)&WhhL[nb1 + kk*32]);
        a0 = __builtin_amdgcn_mfma_f32_16x16x32_bf16(av, b0, a0, 0, 0, 0);
        a1 = __builtin_amdgcn_mfma_f32_16x16x32_bf16(av, b1, a1, 0, 0, 0);
      }
    }
    // publish gate partials + gx to LDS
    {
      float* Gw = GC + w * GC_FSTRIDE;
      #pragma unroll
      for (int r = 0; r < 4; ++r){
        Gw[(lk*4 + r)*36 + lr]      = a0[r];
        Gw[(lk*4 + r)*36 + 16 + lr] = a1[r];
      }
      float* gp = GXS + pb*132 + qg*32 + qj;
      *(f32x4*)gp = pfa;
      *(f32x4*)(gp + 4) = pfb;
    }
    __syncthreads();

    // elementwise LSTM cell: thread owns (b=eb, cols {2*p2, 2*p2+1})
    const bool act = t < mylen;
    const int c0 = 2*p2, c1 = 2*p2 + 1;
    {
      const float gi0 = GC[0*GC_FSTRIDE + eb*36 + c0] + GXS[eb*132 + c0];
      const float gf0 = GC[1*GC_FSTRIDE + eb*36 + c0] + GXS[eb*132 + 32 + c0];
      const float gg0 = GC[2*GC_FSTRIDE + eb*36 + c0] + GXS[eb*132 + 64 + c0];
      const float go0 = GC[3*GC_FSTRIDE + eb*36 + c0] + GXS[eb*132 + 96 + c0];
      const float gi1 = GC[0*GC_FSTRIDE + eb*36 + c1] + GXS[eb*132 + c1];
      const float gf1 = GC[1*GC_FSTRIDE + eb*36 + c1] + GXS[eb*132 + 32 + c1];
      const float gg1 = GC[2*GC_FSTRIDE + eb*36 + c1] + GXS[eb*132 + 64 + c1];
      const float go1 = GC[3*GC_FSTRIDE + eb*36 + c1] + GXS[eb*132 + 96 + c1];
      const float cn0 = sigm(gf0)*cs0 + sigm(gi0)*tanh_f(gg0);
      const float hn0 = sigm(go0) * tanh_f(cn0);
      const float cn1 = sigm(gf1)*cs1 + sigm(gi1)*tanh_f(gg1);
      const float hn1 = sigm(go1) * tanh_f(cn1);
      if (act){ cs0 = cn0; hs0 = hn0; cs1 = cn1; hs1 = hn1; }
    }
    // publish tagged h (frozen value if masked) into next parity slot
    {
      const unsigned hu = (unsigned)f2bf(hs0) | ((unsigned)f2bf(hs1) << 16);
      const unsigned long long hv =
          (unsigned long long)hu | ((unsigned long long)(unsigned)(s_a + 1) << 32);
      h_store_u64(myslot + ((size_t)((s_a + 1) & 1))*16*PAIRS, hv);
    }
    if (act){
      const int bg = grp*16 + eb;
      const int hc = tile*32 + c0;
      if constexpr (LAST){
        float* op = out + ((size_t)t*B_ + bg)*800 + dir*H_ + hc;
        if (hc < H_)     op[0] = hs0;
        if (hc + 1 < H_) op[1] = hs1;
      } else {
        const unsigned hu = (unsigned)f2bf(hs0) | ((unsigned)f2bf(hs1) << 16);
        *(unsigned*)(xn + ((size_t)t*B_ + bg)*832 + (size_t)dir*HP + hc) = hu;
      }
    }
    ++s_a;
  }
}

// ======================= host side =======================
template<typename GXT>
static void run_all(void* const* din, float* out, char* ws, hipStream_t stream)
{
  const float* x      = (const float*)din[0];
  const int* lens     = (const int*)din[1];
  const float* wihf0  = (const float*)din[2];
  const float* wihf12 = (const float*)din[3];
  const float* whhf   = (const float*)din[4];
  const float* bsf    = (const float*)din[5];
  const float* wihb0  = (const float*)din[6];
  const float* wihb12 = (const float*)din[7];
  const float* whhb   = (const float*)din[8];
  const float* bsb    = (const float*)din[9];

  char* p = ws;
  auto alloc = [&](size_t n){ char* r = p; p += (n + 255) & ~(size_t)255; return r; };
  GXT* gx            = (GXT*)alloc((size_t)T_*B_*NW*sizeof(GXT));
  unsigned short* xA = (unsigned short*)alloc((size_t)T_*B_*832*2);
  unsigned short* xB = (unsigned short*)alloc((size_t)T_*B_*832*2);
  unsigned short* wihp = (unsigned short*)alloc((size_t)NW*K12P*2);
  unsigned short* whhp = (unsigned short*)alloc((size_t)2*NTILES*128*424*2);
  float* biasp       = (float*)alloc((size_t)NW*4);
  unsigned long long* hbt = (unsigned long long*)alloc(HBT_BYTES);

  hipMemsetAsync(out, 0, (size_t)T_*B_*800*4, stream);
  {
    size_t n = (size_t)T_*B_*K0P;
    k_conv_x0<<<dim3((unsigned)((n+255)/256)), dim3(256), 0, stream>>>(x, xA);
  }
  hipFuncSetAttribute(reinterpret_cast<const void*>(&lstm_rec<GXT,false>),
                      hipFuncAttributeMaxDynamicSharedMemorySize, LDS_TOTAL);
  hipFuncSetAttribute(reinterpret_cast<const void*>(&lstm_rec<GXT,true>),
                      hipFuncAttributeMaxDynamicSharedMemorySize, LDS_TOTAL);

  const unsigned short* xin[3] = {xA, xB, xA};
  unsigned short* xout[3] = {xB, xA, nullptr};
  const int ldas[3] = {K0P, 832, 832};
  const int Ks[3]   = {K0P, K12P, K12P};

  for (int lyr = 0; lyr < 3; ++lyr){
    const float* wf = (lyr == 0) ? wihf0 : wihf12 + (size_t)(lyr-1)*1600*800;
    const float* wb = (lyr == 0) ? wihb0 : wihb12 + (size_t)(lyr-1)*1600*800;
    {
      size_t n = (size_t)NW*Ks[lyr];
      k_prep_wih<<<dim3((unsigned)((n+255)/256)), dim3(256), 0, stream>>>(
          wf, wb, Ks[lyr], lyr ? 1 : 0, wihp);
    }
    k_prep_bias<<<dim3((NW+255)/256), dim3(256), 0, stream>>>(
        bsf + (size_t)lyr*1600, bsb + (size_t)lyr*1600, biasp);
    gemm_gx<GXT><<<dim3(26, 512), dim3(256), 0, stream>>>(
        xin[lyr], ldas[lyr], Ks[lyr], wihp, biasp, gx, lens);
    {
      size_t n = (size_t)2*NTILES*128*424;
      k_prep_whh<<<dim3((unsigned)((n+255)/256)), dim3(256), 0, stream>>>(
          whhf + (size_t)lyr*1600*400, whhb + (size_t)lyr*1600*400, whhp);
    }
    hipMemsetAsync(hbt, 0, HBT_BYTES, stream);

    const GXT* a_gx = gx;
    const unsigned short* a_whhp = whhp;
    const int* a_lens = lens;
    unsigned long long* a_hbt = hbt;
    unsigned short* a_xn = xout[lyr];
    float* a_out = out;
    void* args[6] = {&a_gx, &a_whhp, &a_lens, &a_hbt, &a_xn, &a_out};
    if (lyr < 2)
      hipLaunchCooperativeKernel(reinterpret_cast<const void*>(&lstm_rec<GXT,false>),
                                 dim3(REC_BLOCKS), dim3(256), args, LDS_TOTAL, stream);
    else
      hipLaunchCooperativeKernel(reinterpret_cast<const void*>(&lstm_rec<GXT,true>),
                                 dim3(REC_BLOCKS), dim3(256), args, LDS_TOTAL, stream);
  }
}

extern "C" void kernel_launch(void* const* d_in, const int* in_sizes, int n_in,
                              void* d_out, int out_size, void* d_ws, size_t ws_size,
                              hipStream_t stream)
{
  (void)in_sizes; (void)n_in; (void)out_size;
  auto align = [](size_t n){ return (n + 255) & ~(size_t)255; };
  const size_t fixed =
      align((size_t)T_*B_*832*2) * 2 +
      align((size_t)NW*K12P*2) +
      align((size_t)2*NTILES*128*424*2) +
      align((size_t)NW*4) +
      align(HBT_BYTES);
  const size_t need32 = align((size_t)T_*B_*NW*4) + fixed;
  const size_t need16 = align((size_t)T_*B_*NW*2) + fixed;

  if (ws_size >= need32)
    run_all<float>(d_in, (float*)d_out, (char*)d_ws, stream);
  else if (ws_size >= need16)
    run_all<unsigned short>(d_in, (float*)d_out, (char*)d_ws, stream);
  else
    hipMemsetAsync(d_out, 0, (size_t)T_*B_*800*4, stream);
}